// Round 3
// baseline (439.275 us; speedup 1.0000x reference)
//
#include <hip/hip_runtime.h>

#define BB    16
#define TT    64
#define F0    8
#define NN    100
#define NEX   15
#define F1    32
#define F2    64
#define HRD   64
#define OUTD  5
#define BT    (BB*TT)        // 1024
#define ZELEMS ((size_t)BT*F0*NEX*NN)   // 12,288,000 floats (49.2 MB)

// ===========================================================================
// Head v3: 4 chains per block share one LDS-staged S[b,t] per t-step.
// Block = (b, g): chains t0 = 1+4g+c, c=0..3. 512 threads = (f2, c2, m).
// S pipeline: loads for t+1 issued before compute(t); ds_write after the
// post-compute barrier (single 40KB buffer, latency hidden by compute).
// ===========================================================================
__global__ __launch_bounds__(512) void head_chain(
    const float* __restrict__ x, const float* __restrict__ S,
    float* __restrict__ zbuf) {
  __shared__ float Sld[NN * NN];       // 40 KB, [n][m]
  __shared__ float zl[4 * NN * F0];    // 12.8 KB, [c][m][f]

  const int blk = blockIdx.x;
  const int b   = blk >> 4;
  const int g   = blk & 15;
  const int tb  = 1 + 4 * g;
  const int te  = min(tb + 17, TT - 1);
  const int tid = threadIdx.x;
  const int m   = tid & 127;
  const int c2  = (tid >> 7) & 1;
  const int f2  = tid >> 8;
  const int f0b = f2 * 4;

  auto act = [&](int T) {
    const int c = T - tb;
    if (c >= 0 && c < 4 && T <= TT - 1 && (c & 1) == c2 && m < NN) {
#pragma unroll
      for (int j = 0; j < 4; ++j)
        zl[c * (NN * F0) + m * F0 + f0b + j] =
            x[((size_t)(b * TT + T - 1) * F0 + f0b + j) * NN + m];
    }
  };

  {
    const float4* Sg = (const float4*)(S + (size_t)(b * TT + tb) * NN * NN);
    float4 R[5];
#pragma unroll
    for (int i = 0; i < 5; ++i) {
      const int idx = tid + i * 512;
      if (idx < 2500) R[i] = Sg[idx];
    }
#pragma unroll
    for (int i = 0; i < 5; ++i) {
      const int idx = tid + i * 512;
      if (idx < 2500) *(float4*)&Sld[idx * 4] = R[i];
    }
  }
  act(tb);

  for (int t = tb; t <= te; ++t) {
    const bool more = (t < te);
    float4 Rn[5];
    if (more) {
      const float4* Sg =
          (const float4*)(S + (size_t)(b * TT + t + 1) * NN * NN);
#pragma unroll
      for (int i = 0; i < 5; ++i) {
        const int idx = tid + i * 512;
        if (idx < 2500) Rn[i] = Sg[idx];
      }
    }
    __syncthreads();

    const int t0a = tb + c2;
    const int t0b = tb + c2 + 2;
    const bool a0 = (t >= t0a) && (t <= t0a + 14);
    const bool a1 = (t >= t0b) && (t <= t0b + 14) && (t0b <= TT - 1);

    float acc0[4] = {0.f, 0.f, 0.f, 0.f};
    float acc1[4] = {0.f, 0.f, 0.f, 0.f};
    if (m < NN) {
      const float* zA = &zl[c2 * (NN * F0) + f0b];
      const float* zB = &zl[(c2 + 2) * (NN * F0) + f0b];
      if (a0 && a1) {
#pragma unroll 10
        for (int n = 0; n < NN; ++n) {
          const float s = Sld[n * NN + m];
          const float4 z0 = *(const float4*)&zA[n * F0];
          const float4 z1 = *(const float4*)&zB[n * F0];
          acc0[0] += z0.x * s; acc0[1] += z0.y * s;
          acc0[2] += z0.z * s; acc0[3] += z0.w * s;
          acc1[0] += z1.x * s; acc1[1] += z1.y * s;
          acc1[2] += z1.z * s; acc1[3] += z1.w * s;
        }
      } else if (a0) {
#pragma unroll 10
        for (int n = 0; n < NN; ++n) {
          const float s = Sld[n * NN + m];
          const float4 z0 = *(const float4*)&zA[n * F0];
          acc0[0] += z0.x * s; acc0[1] += z0.y * s;
          acc0[2] += z0.z * s; acc0[3] += z0.w * s;
        }
      } else if (a1) {
#pragma unroll 10
        for (int n = 0; n < NN; ++n) {
          const float s = Sld[n * NN + m];
          const float4 z1 = *(const float4*)&zB[n * F0];
          acc1[0] += z1.x * s; acc1[1] += z1.y * s;
          acc1[2] += z1.z * s; acc1[3] += z1.w * s;
        }
      }
    }
    __syncthreads();

    if (m < NN) {
      if (a0) {
        *(float4*)&zl[c2 * (NN * F0) + m * F0 + f0b] =
            make_float4(acc0[0], acc0[1], acc0[2], acc0[3]);
        const int k = t - t0a;
#pragma unroll
        for (int j = 0; j < 4; ++j)
          zbuf[(((size_t)(b * TT + t) * F0 + f0b + j) * NEX + k) * NN + m] =
              acc0[j];
      }
      if (a1) {
        *(float4*)&zl[(c2 + 2) * (NN * F0) + m * F0 + f0b] =
            make_float4(acc1[0], acc1[1], acc1[2], acc1[3]);
        const int k = t - t0b;
#pragma unroll
        for (int j = 0; j < 4; ++j)
          zbuf[(((size_t)(b * TT + t) * F0 + f0b + j) * NEX + k) * NN + m] =
              acc1[j];
      }
    }
    act(t + 1);
    if (more) {
#pragma unroll
      for (int i = 0; i < 5; ++i) {
        const int idx = tid + i * 512;
        if (idx < 2500) *(float4*)&Sld[idx * 4] = Rn[i];
      }
    }
  }
}

// ===========================================================================
// Fused tail: one block per bt (1024 blocks, 512 threads, 128 KB LDS).
// LDS (floats): [0,19200) y1[32][6][100] (reused as h[64][100]);
//               [19200,32000) zt[8][16][100] (reused as y2[128][100]).
// ===========================================================================
__global__ __launch_bounds__(512) void tail_fused(
    const float* __restrict__ x, const float* __restrict__ zbuf,
    const float* __restrict__ w1,  const float* __restrict__ b1,
    const float* __restrict__ w2,  const float* __restrict__ b2,
    const float* __restrict__ fw1, const float* __restrict__ fb1,
    const float* __restrict__ fw2, const float* __restrict__ fb2,
    float* __restrict__ out) {
  __shared__ float lds[32000];
  float* y1 = lds;            // 19200 floats
  float* zt = lds + 19200;    // 12800 floats
  float* y2 = lds + 19200;    // reuses zt slot after conv1
  float* hb = lds;            // reuses y1 slot after conv2

  const int bt  = blockIdx.x;
  const int t   = bt & (TT - 1);
  const int tid = threadIdx.x;
  const int n   = tid & 127;
  const int sg  = tid >> 7;

  // ---- stage z[ci][k][n] ----
  if (n < NN) {
    for (int ci = 0; ci < F0; ++ci) {
#pragma unroll
      for (int k = sg; k < 16; k += 4) {
        float v;
        if (k == 0)      v = x[((size_t)bt * F0 + ci) * NN + n];
        else if (k <= t) v = zbuf[(((size_t)bt * F0 + ci) * NEX + (k - 1)) * NN + n];
        else             v = 0.f;
        zt[ci * 1600 + k * NN + n] = v;
      }
    }
  }
  __syncthreads();

  // ---- conv1 + ReLU + pool2 -> y1 ----
  {
    float acc[8][12];
#pragma unroll
    for (int j = 0; j < 8; ++j) {
      const float bias = b1[sg * 8 + j];
#pragma unroll
      for (int l = 0; l < 12; ++l) acc[j][l] = bias;
    }
    if (n < NN) {
      for (int ci = 0; ci < F0; ++ci) {
        float zv[15];
#pragma unroll
        for (int k = 0; k < 15; ++k) zv[k] = zt[ci * 1600 + k * NN + n];
#pragma unroll
        for (int j = 0; j < 8; ++j)
#pragma unroll
          for (int kk = 0; kk < 4; ++kk) {
            const float w = w1[((sg * 8 + j) * F0 + ci) * 4 + kk];
#pragma unroll
            for (int l = 0; l < 12; ++l) acc[j][l] += zv[l + kk] * w;
          }
      }
#pragma unroll
      for (int j = 0; j < 8; ++j)
#pragma unroll
        for (int p = 0; p < 6; ++p)
          y1[(sg * 8 + j) * 600 + p * NN + n] =
              fmaxf(fmaxf(acc[j][2 * p], acc[j][2 * p + 1]), 0.f);
    }
  }
  __syncthreads();

  // ---- conv2 + ReLU + pool2 -> y2 (zt slot; zt is dead) ----
  {
    float acc[16][4];
#pragma unroll
    for (int j = 0; j < 16; ++j) {
      const float bb = b2[sg * 16 + j];
#pragma unroll
      for (int l = 0; l < 4; ++l) acc[j][l] = bb;
    }
    if (n < NN) {
      for (int ci = 0; ci < F1; ++ci) {
        float yv[6];
#pragma unroll
        for (int l = 0; l < 6; ++l) yv[l] = y1[ci * 600 + l * NN + n];
#pragma unroll
        for (int j = 0; j < 16; ++j)
#pragma unroll
          for (int kk = 0; kk < 3; ++kk) {
            const float w = w2[((sg * 16 + j) * F1 + ci) * 3 + kk];
#pragma unroll
            for (int l = 0; l < 4; ++l) acc[j][l] += yv[l + kk] * w;
          }
      }
#pragma unroll
      for (int j = 0; j < 16; ++j) {
        const int d0 = (sg * 16 + j) * 2;
        y2[(d0 + 0) * NN + n] = fmaxf(fmaxf(acc[j][0], acc[j][1]), 0.f);
        y2[(d0 + 1) * NN + n] = fmaxf(fmaxf(acc[j][2], acc[j][3]), 0.f);
      }
    }
  }
  __syncthreads();

  // ---- fc1 (128->64, ReLU) -> hb (y1 slot; y1 is dead) ----
  if (n < NN) {
    float v[128];
#pragma unroll
    for (int d = 0; d < 128; ++d) v[d] = y2[d * NN + n];
#pragma unroll
    for (int jj = 0; jj < 16; ++jj) {
      const int j = sg * 16 + jj;
      const float* wr = fw1 + j * 128;
      float s0 = 0.f, s1 = 0.f, s2 = 0.f, s3 = 0.f;
#pragma unroll
      for (int d = 0; d < 128; d += 4) {
        s0 += v[d + 0] * wr[d + 0];
        s1 += v[d + 1] * wr[d + 1];
        s2 += v[d + 2] * wr[d + 2];
        s3 += v[d + 3] * wr[d + 3];
      }
      hb[j * NN + n] = fmaxf((s0 + s1) + (s2 + s3) + fb1[j], 0.f);
    }
  }
  __syncthreads();

  // ---- fc2 (64->5) -> out ----
  if (tid < OUTD * NN) {
    const int q  = tid / NN;
    const int n2 = tid - q * NN;
    float o = fb2[q];
#pragma unroll
    for (int j = 0; j < HRD; ++j) o += hb[j * NN + n2] * fw2[q * HRD + j];
    out[((size_t)bt * OUTD + q) * NN + n2] = o;
  }
}

// ===========================================================================
extern "C" void kernel_launch(void* const* d_in, const int* in_sizes, int n_in,
                              void* d_out, int out_size, void* d_ws,
                              size_t ws_size, hipStream_t stream) {
  const float* x   = (const float*)d_in[0];
  const float* S   = (const float*)d_in[1];
  const float* w1  = (const float*)d_in[2];
  const float* b1  = (const float*)d_in[3];
  const float* w2  = (const float*)d_in[4];
  const float* b2  = (const float*)d_in[5];
  const float* fw1 = (const float*)d_in[6];
  const float* fb1 = (const float*)d_in[7];
  const float* fw2 = (const float*)d_in[8];
  const float* fb2 = (const float*)d_in[9];

  float* zbuf = (float*)d_ws;          // 49.2 MB
  float* outp = (float*)d_out;

  head_chain<<<BB * 16, 512, 0, stream>>>(x, S, zbuf);
  tail_fused<<<BT, 512, 0, stream>>>(x, zbuf, w1, b1, w2, b2, fw1, fb1, fw2,
                                     fb2, outp);
}